// Round 13
// baseline (344.609 us; speedup 1.0000x reference)
//
#include <hip/hip_runtime.h>
#include <math.h>

// Problem constants: N=200 LSTMs, B=100, T=256, D=5 (io), H=20 (units)
constexpr int NL = 200;
constexpr int B  = 100;
constexpr int T  = 256;
constexpr int D  = 5;
constexpr int H  = 20;
constexpr int NW   = 7;      // 16-batch groups per LSTM; 7*16=112 >= 100
constexpr int BPAD = 112;    // padded batch dim of xe (zeros for b>=100)

// K=32 bijection (A and B share it positionally, so any bijection is valid):
//   k = 8*g4 + j ; j in 0..4  -> hh = 4*j + g4   (lane-local recurrence!)
//   g4=0: j5,j6,j7 = x0,x1,x2 ; g4=1: j5,j6 = x3,x4, j7 = bias(1.0)
//   g4=2,3: j>=5 -> 0
// Lane (g4,c16) C-output rows 4*g4+reg give gates of hh=4*Mt+g4 -> the SAME
// lane owns exactly the hh values (hh mod 4 == g4) its next-step B-fragment
// needs: the h state never leaves the lane's registers.

typedef float  f32x4  __attribute__((ext_vector_type(4)));
typedef short  bf16x8 __attribute__((ext_vector_type(8)));

#if __has_builtin(__builtin_amdgcn_exp2f)
__device__ __forceinline__ float exp2fast(float x) { return __builtin_amdgcn_exp2f(x); }
#else
__device__ __forceinline__ float exp2fast(float x) { return __expf(x * 0.6931471805599453f); }
#endif

// Reciprocal on the VALU pipe (NOT v_rcp, which shares the quarter-rate trans
// unit with v_exp): bit-trick seed (~3.5% err) + 2 Newton iters -> ~1.5e-6 rel
// err. 5 VALU insts @2cy vs 1 trans inst @~16cy. Caller guarantees y in
// [1, 2^30] (exp2 args are upper-clamped), so the seed is always valid.
__device__ __forceinline__ float rcp_nt(float y) {
    float x = __int_as_float(0x7EF311C3 - __float_as_int(y));
    x = x * fmaf(-y, x, 2.0f);
    x = x * fmaf(-y, x, 2.0f);
    return x;
}
// exp2 with one-sided clamp: arg>=30 saturates the gate exactly (sigma<1e-9,
// tanh==1 to fp32) and keeps 1+exp2 finite for rcp_nt's bit-trick seed.
__device__ __forceinline__ float expc(float a) {
    return exp2fast(fminf(a, 30.0f));
}

// fp32 -> bf16 bits, round-to-nearest-even
__device__ __forceinline__ unsigned short f2bf(float f) {
    union { float f; unsigned u; } v; v.f = f;
    unsigned r = v.u + 0x7fffu + ((v.u >> 16) & 1u);
    return (unsigned short)(r >> 16);
}
__device__ __forceinline__ unsigned pk2bf(float lo, float hi) {
    return (unsigned)f2bf(lo) | ((unsigned)f2bf(hi) << 16);
}

constexpr float NLOG2E = -1.4426950408889634f;
constexpr float TLOG2E = 2.8853900817779268f;   // 2*log2(e)

__global__ __launch_bounds__(256) void init_out_kernel(const float* __restrict__ dense_b,
                                                       float* __restrict__ out, int n) {
    int i = blockIdx.x * 256 + threadIdx.x;
    if (i < n) out[i] = dense_b[i % D];
}

// xe[g][t][b] (g=0,1): per-lane x/bias fragment pieces, [t][b] order so a
// wave's 16 consecutive b lanes read one 128B line per g.
//   g=0: {bf16(x0)<<16, pk(x1,x2)}   g=1: {bf16(x3)<<16, pk(x4,1.0)}
__global__ __launch_bounds__(256) void xpack_kernel(const float* __restrict__ x,
                                                    int2* __restrict__ xe) {
    int i = blockIdx.x * 256 + threadIdx.x;
    if (i >= 2 * T * BPAD) return;
    const int g = i / (T * BPAD);
    const int r = i % (T * BPAD);
    const int t = r / BPAD;
    const int b = r % BPAD;
    int2 v = {0, 0};
    if (b < B) {
        const float* s = x + ((size_t)b * T + t) * D;
        if (g == 0) { v.x = (int)((unsigned)f2bf(s[0]) << 16); v.y = (int)pk2bf(s[1], s[2]); }
        else        { v.x = (int)((unsigned)f2bf(s[3]) << 16); v.y = (int)pk2bf(s[4], 1.0f); }
    }
    xe[i] = v;
}

__device__ __forceinline__ float lstm_act(const f32x4 a, float& c) {
    // a = {-z_i, -z_f, 2*z_g, -z_o} * log2e (bias folded into MFMA A)
    const float iv = rcp_nt(1.0f + expc(a[0]));
    const float fv = rcp_nt(1.0f + expc(a[1]));
    const float gv = fmaf(-2.0f, rcp_nt(expc(a[2]) + 1.0f), 1.0f);
    const float ov = rcp_nt(1.0f + expc(a[3]));
    c = fmaf(fv, c, iv * gv);
    const float th = fmaf(-2.0f, rcp_nt(expc(TLOG2E * c) + 1.0f), 1.0f);
    return ov * th;
}

// ONE 64-thread wave per (lstm n, 16-batch group w). Entire recurrence in
// registers: no LDS, no barriers, no cross-lane ops. Per step: pack bfrag
// (3 cvt_pk + or), 6 MFMAs (5 gate tiles + 1 dense), 5 activation chains
// (25 exp2 on trans pipe + Newton rcp on VALU pipe), 5 coalesced dense
// stores, 1 x-fragment prefetch.
template<bool USE_WS>
__global__ __attribute__((amdgpu_flat_work_group_size(64, 64),
                          amdgpu_waves_per_eu(1, 2)))
void lstm_reg_kernel(
    const int2*  __restrict__ xe,   // [2][T][BPAD] packed x pieces
    const float* __restrict__ Wg,   // [N][D][4H]
    const float* __restrict__ Ug,   // [N][H][4H]
    const float* __restrict__ bg,   // [N][4H]
    const float* __restrict__ dWg,  // [N*H][D]
    float* __restrict__ pw,         // [N][T][D][B] partials (USE_WS)
    float* __restrict__ out)        // [B][T][D] (atomic fallback)
{
    const int blk = blockIdx.x;            // 0..1399
    const int n   = blk / NW;
    const int w   = blk % NW;
    const int l   = threadIdx.x;           // 0..63
    const int c16 = l & 15;
    const int g4  = l >> 4;

    const float* Un = Ug  + (size_t)n * H * 4 * H;
    const float* Wn = Wg  + (size_t)n * D * 4 * H;
    const float* bn = bg  + (size_t)n * 4 * H;
    const float* dn = dWg + (size_t)n * H * D;

    // ---- recurrence A fragments (Mt = 0..4), element j <-> k = 8*g4 + j ----
    const int gateA = c16 & 3;
    const int hA4   = c16 >> 2;
    const float sA  = (gateA == 2) ? TLOG2E : NLOG2E;
    bf16x8 af0, af1, af2, af3, af4;
    {
        auto build = [&](int Mt) {
            const int colA = gateA * H + (Mt * 4 + hA4);
            bf16x8 a;
            #pragma unroll
            for (int j = 0; j < 8; ++j) {
                float v = 0.0f;
                if (j < 5) {                         // h rows: hh = 4*j + g4
                    v = Un[(4 * j + g4) * 4 * H + colA];
                } else if (g4 == 0) {                // x rows 0..2
                    v = Wn[(j - 5) * 4 * H + colA];
                } else if (g4 == 1) {                // x rows 3,4 + bias
                    v = (j < 7) ? Wn[(j - 2) * 4 * H + colA] : bn[colA];
                }
                a[j] = (short)f2bf(sA * v);
            }
            return a;
        };
        af0 = build(0); af1 = build(1); af2 = build(2); af3 = build(3); af4 = build(4);
    }
    // ---- dense A fragment: rows c16<5 = d, h rows only ----
    bf16x8 afd;
    #pragma unroll
    for (int j = 0; j < 8; ++j) {
        float v = 0.0f;
        if (c16 < D && j < 5) v = dn[(4 * j + g4) * D + c16];
        afd[j] = (short)f2bf(v);
    }

    const int  bgl    = w * 16 + c16;          // 0..111 (pad cols compute junk, never stored)
    const bool bvalid = bgl < B;
    const int2* xlane = xe + (size_t)(g4 & 1) * T * BPAD + bgl;   // valid for g4<2
    float* pbase = USE_WS ? (pw + (size_t)n * T * (D * B) + bgl)
                          : (out + (size_t)bgl * T * D);

    int2 xfA = {0, 0}, xfB = {0, 0};
    if (g4 < 2) {
        xfA = xlane[0];
        xfB = xlane[BPAD];                     // t = 1
    }

    float h0 = 0.f, h1 = 0.f, h2 = 0.f, h3 = 0.f, h4 = 0.f;
    float c0 = 0.f, c1 = 0.f, c2 = 0.f, c3 = 0.f, c4 = 0.f;
    const f32x4 z4 = {0.f, 0.f, 0.f, 0.f};
    const float fzero = 0.0f;

    auto body = [&](int2& xf, int t) {
        // pack B fragment: [h(t-1) | x(t) | bias]
        unsigned w0, w1, w2;
        asm("v_cvt_pk_bf16_f32 %0, %1, %2" : "=v"(w0) : "v"(h0), "v"(h1));
        asm("v_cvt_pk_bf16_f32 %0, %1, %2" : "=v"(w1) : "v"(h2), "v"(h3));
        asm("v_cvt_pk_bf16_f32 %0, %1, %2" : "=v"(w2) : "v"(h4), "v"(fzero));
        w2 |= (unsigned)xf.x;
        union { int4 i; bf16x8 v; } ub;
        ub.i = make_int4((int)w0, (int)w1, (int)w2, xf.y);
        const bf16x8 bfrag = ub.v;

        // 6 MFMAs
        const f32x4 ad = __builtin_amdgcn_mfma_f32_16x16x32_bf16(afd, bfrag, z4, 0, 0, 0);
        const f32x4 a0 = __builtin_amdgcn_mfma_f32_16x16x32_bf16(af0, bfrag, z4, 0, 0, 0);
        const f32x4 a1 = __builtin_amdgcn_mfma_f32_16x16x32_bf16(af1, bfrag, z4, 0, 0, 0);
        const f32x4 a2 = __builtin_amdgcn_mfma_f32_16x16x32_bf16(af2, bfrag, z4, 0, 0, 0);
        const f32x4 a3 = __builtin_amdgcn_mfma_f32_16x16x32_bf16(af3, bfrag, z4, 0, 0, 0);
        const f32x4 a4 = __builtin_amdgcn_mfma_f32_16x16x32_bf16(af4, bfrag, z4, 0, 0, 0);

        // prefetch x fragment for t+2 (consumed two bodies later)
        if (g4 < 2) {
            const int tc = (t + 2 < T) ? t + 2 : T - 1;
            xf = xlane[(size_t)tc * BPAD];
        }

        // dense result is for step t-1 (bfrag held h(t-1))
        if (t > 0) {
            if (USE_WS) {
                float* pt = pbase + (size_t)(t - 1) * (D * B);
                if (bvalid && g4 == 0) {
                    pt[0 * B] = ad[0]; pt[1 * B] = ad[1];
                    pt[2 * B] = ad[2]; pt[3 * B] = ad[3];
                } else if (bvalid && g4 == 1) {
                    pt[4 * B] = ad[0];
                }
            } else {
                float* pt = pbase + (size_t)(t - 1) * D;
                if (bvalid && g4 == 0) {
                    atomicAdd(&pt[0], ad[0]); atomicAdd(&pt[1], ad[1]);
                    atomicAdd(&pt[2], ad[2]); atomicAdd(&pt[3], ad[3]);
                } else if (bvalid && g4 == 1) {
                    atomicAdd(&pt[4], ad[0]);
                }
            }
        }

        // activations -> h(t), c(t)  (lane-local; feeds next body's pack)
        h0 = lstm_act(a0, c0);
        h1 = lstm_act(a1, c1);
        h2 = lstm_act(a2, c2);
        h3 = lstm_act(a3, c3);
        h4 = lstm_act(a4, c4);
    };

    for (int t = 0; t < T; t += 2) {
        body(xfA, t);
        body(xfB, t + 1);
    }

    // final dense for h(T-1)
    {
        unsigned w0, w1, w2;
        asm("v_cvt_pk_bf16_f32 %0, %1, %2" : "=v"(w0) : "v"(h0), "v"(h1));
        asm("v_cvt_pk_bf16_f32 %0, %1, %2" : "=v"(w1) : "v"(h2), "v"(h3));
        asm("v_cvt_pk_bf16_f32 %0, %1, %2" : "=v"(w2) : "v"(h4), "v"(fzero));
        union { int4 i; bf16x8 v; } ub;
        ub.i = make_int4((int)w0, (int)w1, (int)w2, 0);
        const f32x4 ad = __builtin_amdgcn_mfma_f32_16x16x32_bf16(afd, ub.v, z4, 0, 0, 0);
        if (USE_WS) {
            float* pt = pbase + (size_t)(T - 1) * (D * B);
            if (bvalid && g4 == 0) {
                pt[0 * B] = ad[0]; pt[1 * B] = ad[1];
                pt[2 * B] = ad[2]; pt[3 * B] = ad[3];
            } else if (bvalid && g4 == 1) {
                pt[4 * B] = ad[0];
            }
        } else {
            float* pt = pbase + (size_t)(T - 1) * D;
            if (bvalid && g4 == 0) {
                atomicAdd(&pt[0], ad[0]); atomicAdd(&pt[1], ad[1]);
                atomicAdd(&pt[2], ad[2]); atomicAdd(&pt[3], ad[3]);
            } else if (bvalid && g4 == 1) {
                atomicAdd(&pt[4], ad[0]);
            }
        }
    }
}

// out[b][t][d] = dense_b[d] + sum_n pw[n][t][d][b]  (coalesced reads)
__global__ __launch_bounds__(512) void reduce_kernel(
    const float* __restrict__ pw, const float* __restrict__ dense_b,
    float* __restrict__ out)
{
    const int t    = blockIdx.x;
    const int flat = threadIdx.x;              // d*B + b, 0..499
    if (flat >= B * D) return;
    const int d = flat / B;
    const int b = flat % B;
    const float* p = pw + (size_t)t * (D * B) + flat;
    constexpr size_t stride = (size_t)T * D * B;
    float a0 = 0.0f, a1 = 0.0f;
    #pragma unroll 10
    for (int n = 0; n < NL; n += 2) {
        a0 += p[(size_t)n * stride];
        a1 += p[(size_t)(n + 1) * stride];
    }
    out[((size_t)b * T + t) * D + d] = a0 + a1 + dense_b[d];
}

extern "C" void kernel_launch(void* const* d_in, const int* in_sizes, int n_in,
                              void* d_out, int out_size, void* d_ws, size_t ws_size,
                              hipStream_t stream) {
    const float* x   = (const float*)d_in[0];
    const float* Wg  = (const float*)d_in[1];
    const float* Ug  = (const float*)d_in[2];
    const float* bg  = (const float*)d_in[3];
    const float* dWg = (const float*)d_in[4];
    const float* dbv = (const float*)d_in[5];
    float* out = (float*)d_out;

    const size_t xe_bytes = (size_t)2 * T * BPAD * sizeof(int2);      // 458,752
    const size_t pw_bytes = (size_t)NL * T * D * B * sizeof(float);   // 102.4 MB

    int2* xe = (int2*)d_ws;
    xpack_kernel<<<(2 * T * BPAD + 255) / 256, 256, 0, stream>>>(x, xe);

    if (ws_size >= xe_bytes + pw_bytes) {
        float* pw = (float*)((char*)d_ws + xe_bytes);
        lstm_reg_kernel<true><<<NL * NW, 64, 0, stream>>>(xe, Wg, Ug, bg, dWg, pw, out);
        reduce_kernel<<<T, 512, 0, stream>>>(pw, dbv, out);
    } else {
        init_out_kernel<<<(out_size + 255) / 256, 256, 0, stream>>>(dbv, out, out_size);
        lstm_reg_kernel<false><<<NL * NW, 64, 0, stream>>>(xe, Wg, Ug, bg, dWg, nullptr, out);
    }
}

// Round 14
// 252.219 us; speedup vs baseline: 1.3663x; 1.3663x over previous
//
#include <hip/hip_runtime.h>
#include <math.h>

// Problem constants: N=200 LSTMs, B=100, T=256, D=5 (io), H=20 (units)
constexpr int NL = 200;
constexpr int B  = 100;
constexpr int T  = 256;
constexpr int D  = 5;
constexpr int H  = 20;
constexpr int NW   = 7;      // 16-batch groups per LSTM; 7*16=112 >= 100
constexpr int BPAD = 112;    // padded batch dim of xe (zeros for b>=100)
constexpr int RP   = 40;     // LDS row pitch in shorts (80 B): banks spread, 16B-aligned

// K=32 bijection (A and B share it positionally, so any bijection is valid):
//   k = 8*g4 + j ; j in 0..4 -> hh = 4*j + g4
//   g4=0: j5,j6,j7 = x0,x1,x2 ; g4=1: j5,j6 = x3,x4, j7 = bias(1.0)
//   g4=2,3: j>=5 -> 0
// Tile Mt output: lane (g4,c16) gets gates of hh = 4*Mt + g4, i.e. j-slot Mt.
// Wave0 computes Mt=0,1 (j-slots 0,1) + dense; wave1 computes Mt=2,3,4
// (j-slots 2,3,4). h exchanged via LDS; x/bias OR'd from registers at read.

typedef float  f32x4  __attribute__((ext_vector_type(4)));
typedef short  bf16x8 __attribute__((ext_vector_type(8)));

__device__ __forceinline__ float rcpf(float x) { return __builtin_amdgcn_rcpf(x); }

#if __has_builtin(__builtin_amdgcn_exp2f)
__device__ __forceinline__ float exp2fast(float x) { return __builtin_amdgcn_exp2f(x); }
#else
__device__ __forceinline__ float exp2fast(float x) { return __expf(x * 0.6931471805599453f); }
#endif

// fp32 -> bf16 bits, round-to-nearest-even
__device__ __forceinline__ unsigned short f2bf(float f) {
    union { float f; unsigned u; } v; v.f = f;
    unsigned r = v.u + 0x7fffu + ((v.u >> 16) & 1u);
    return (unsigned short)(r >> 16);
}
__device__ __forceinline__ unsigned pk2bf(float lo, float hi) {
    return (unsigned)f2bf(lo) | ((unsigned)f2bf(hi) << 16);
}

// LDS-only block barrier (dense stores / x prefetch stay in flight)
__device__ __forceinline__ void block_sync_lds() {
    asm volatile("s_waitcnt lgkmcnt(0)" ::: "memory");
    __builtin_amdgcn_s_barrier();
}

constexpr float NLOG2E = -1.4426950408889634f;
constexpr float TLOG2E = 2.8853900817779268f;   // 2*log2(e)

__global__ __launch_bounds__(256) void init_out_kernel(const float* __restrict__ dense_b,
                                                       float* __restrict__ out, int n) {
    int i = blockIdx.x * 256 + threadIdx.x;
    if (i < n) out[i] = dense_b[i % D];
}

// xe[g][t][b] (g=0,1): per-lane x/bias fragment pieces ([t][b] order).
//   g=0: {bf16(x0)<<16, pk(x1,x2)}   g=1: {bf16(x3)<<16, pk(x4,1.0)}
__global__ __launch_bounds__(256) void xpack_kernel(const float* __restrict__ x,
                                                    int2* __restrict__ xe) {
    int i = blockIdx.x * 256 + threadIdx.x;
    if (i >= 2 * T * BPAD) return;
    const int g = i / (T * BPAD);
    const int r = i % (T * BPAD);
    const int t = r / BPAD;
    const int b = r % BPAD;
    int2 v = {0, 0};
    if (b < B) {
        const float* s = x + ((size_t)b * T + t) * D;
        if (g == 0) { v.x = (int)((unsigned)f2bf(s[0]) << 16); v.y = (int)pk2bf(s[1], s[2]); }
        else        { v.x = (int)((unsigned)f2bf(s[3]) << 16); v.y = (int)pk2bf(s[4], 1.0f); }
    }
    xe[i] = v;
}

__device__ __forceinline__ float lstm_act(const f32x4 a, float& c) {
    // a = {-z_i, -z_f, 2*z_g, -z_o} * log2e (bias folded into MFMA A)
    const float iv = rcpf(1.0f + exp2fast(a[0]));
    const float fv = rcpf(1.0f + exp2fast(a[1]));
    const float gv = fmaf(-2.0f, rcpf(exp2fast(a[2]) + 1.0f), 1.0f);
    const float ov = rcpf(1.0f + exp2fast(a[3]));
    c = fmaf(fv, c, iv * gv);
    const float th = fmaf(-2.0f, rcpf(exp2fast(TLOG2E * c) + 1.0f), 1.0f);
    return ov * th;
}

// One block = 2 waves per (lstm n, 16-batch group w). Wave0: gate tiles
// Mt=0,1 + dense MFMA + dense stores + acts for j-slots 0,1. Wave1: gate
// tiles Mt=2,3,4 + acts for j-slots 2,3,4. h state double-buffered in LDS
// (b128 read; b32/b16 writes); x/bias OR'd from registers after the read.
// ONE lgkm-only barrier per step.
template<bool USE_WS>
__global__ __attribute__((amdgpu_flat_work_group_size(128, 128),
                          amdgpu_waves_per_eu(1, 4)))
void lstm2w_kernel(
    const int2*  __restrict__ xe,   // [2][T][BPAD] packed x pieces
    const float* __restrict__ Wg,   // [N][D][4H]
    const float* __restrict__ Ug,   // [N][H][4H]
    const float* __restrict__ bg,   // [N][4H]
    const float* __restrict__ dWg,  // [N*H][D]
    float* __restrict__ pw,         // [N][T][D][B] partials (USE_WS)
    float* __restrict__ out)        // [B][T][D] (atomic fallback)
{
    const int blk = blockIdx.x;            // 0..1399
    const int n   = blk / NW;
    const int w   = blk % NW;
    const int tid = threadIdx.x;
    const int wid = tid >> 6;              // 0 or 1
    const int l   = tid & 63;
    const int c16 = l & 15;
    const int g4  = l >> 4;

    __shared__ __align__(16) short hbuf[2][16][RP];   // 2.5 KB, h region only

    for (int i = tid; i < 2 * 16 * RP / 2; i += 128)
        ((int*)&hbuf[0][0][0])[i] = 0;

    const float* Un = Ug  + (size_t)n * H * 4 * H;
    const float* Wn = Wg  + (size_t)n * D * 4 * H;
    const float* bn = bg  + (size_t)n * 4 * H;
    const float* dn = dWg + (size_t)n * H * D;

    // ---- A fragments, element j <-> k = 8*g4 + j (round-12 bijection) ----
    const int gateA = c16 & 3;
    const int hA4   = c16 >> 2;
    const float sA  = (gateA == 2) ? TLOG2E : NLOG2E;
    auto build = [&](int Mt) {
        const int colA = gateA * H + (Mt * 4 + hA4);
        bf16x8 a;
        #pragma unroll
        for (int j = 0; j < 8; ++j) {
            float v = 0.0f;
            if (j < 5) {                         // h rows: hh = 4*j + g4
                v = Un[(4 * j + g4) * 4 * H + colA];
            } else if (g4 == 0) {                // x rows 0..2
                v = Wn[(j - 5) * 4 * H + colA];
            } else if (g4 == 1) {                // x rows 3,4 + bias
                v = (j < 7) ? Wn[(j - 2) * 4 * H + colA] : bn[colA];
            }
            a[j] = (short)f2bf(sA * v);
        }
        return a;
    };
    bf16x8 afX, afY, afZ;
    if (wid == 0) {
        afX = build(0); afY = build(1);
        // dense A: rows c16<5 = d, h rows only
        #pragma unroll
        for (int j = 0; j < 8; ++j) {
            float v = 0.0f;
            if (c16 < D && j < 5) v = dn[(4 * j + g4) * D + c16];
            afZ[j] = (short)f2bf(v);
        }
    } else {
        afX = build(2); afY = build(3); afZ = build(4);
    }

    const int  bgl    = w * 16 + c16;
    const bool bvalid = bgl < B;
    const int2* xlane = xe + (size_t)(g4 & 1) * T * BPAD + bgl;   // valid for g4<2
    float* pbase = USE_WS ? (pw + (size_t)n * T * (D * B) + bgl)
                          : (out + (size_t)bgl * T * D);

    char* lb = (char*)&hbuf[0][0][0];
    const int rdo  = c16 * (RP * 2) + g4 * 16;     // 16B-aligned b128 read
    const int wo01 = rdo;                          // wave0 b32 (j=0,1)
    const int wo23 = rdo + 4;                      // wave1 b32 (j=2,3)
    const int wo4  = rdo + 8;                      // wave1 b16 (j=4)
    constexpr int BUF = 16 * RP * 2;               // bytes per buffer

    __syncthreads();                               // zero-init visible

    int2 xfA = {0, 0}, xfB = {0, 0};
    if (g4 < 2) { xfA = xlane[0]; xfB = xlane[BPAD]; }

    float cA = 0.f, cB = 0.f, cC = 0.f;
    const f32x4 z4 = {0.f, 0.f, 0.f, 0.f};
    const float fzero = 0.0f;

    auto body = [&](int2& xf, int t, int p) {
        // B fragment: h(t-1) from LDS, x(t)/bias OR'd from registers
        int4 hv = *(const int4*)(lb + p * BUF + rdo);
        hv.z |= xf.x;                              // j5 (hi short)
        hv.w |= xf.y;                              // j6,j7
        union { int4 i; bf16x8 v; } ub; ub.i = hv;
        const bf16x8 bfrag = ub.v;

        const f32x4 aX = __builtin_amdgcn_mfma_f32_16x16x32_bf16(afX, bfrag, z4, 0, 0, 0);
        const f32x4 aY = __builtin_amdgcn_mfma_f32_16x16x32_bf16(afY, bfrag, z4, 0, 0, 0);
        const f32x4 aZ = __builtin_amdgcn_mfma_f32_16x16x32_bf16(afZ, bfrag, z4, 0, 0, 0);

        // prefetch x fragment for t+2
        if (g4 < 2) {
            const int tc = (t + 2 < T) ? t + 2 : T - 1;
            xf = xlane[(size_t)tc * BPAD];
        }

        if (wid == 0) {
            // dense result (aZ) is for step t-1
            if (t > 0) {
                if (USE_WS) {
                    float* pt = pbase + (size_t)(t - 1) * (D * B);
                    if (bvalid && g4 == 0) {
                        pt[0 * B] = aZ[0]; pt[1 * B] = aZ[1];
                        pt[2 * B] = aZ[2]; pt[3 * B] = aZ[3];
                    } else if (bvalid && g4 == 1) {
                        pt[4 * B] = aZ[0];
                    }
                } else {
                    float* pt = pbase + (size_t)(t - 1) * D;
                    if (bvalid && g4 == 0) {
                        atomicAdd(&pt[0], aZ[0]); atomicAdd(&pt[1], aZ[1]);
                        atomicAdd(&pt[2], aZ[2]); atomicAdd(&pt[3], aZ[3]);
                    } else if (bvalid && g4 == 1) {
                        atomicAdd(&pt[4], aZ[0]);
                    }
                }
            }
            const float h0 = lstm_act(aX, cA);
            const float h1 = lstm_act(aY, cB);
            unsigned w0;
            asm("v_cvt_pk_bf16_f32 %0, %1, %2" : "=v"(w0) : "v"(h0), "v"(h1));
            *(unsigned*)(lb + (p ^ 1) * BUF + wo01) = w0;
        } else {
            const float h2 = lstm_act(aX, cA);
            const float h3 = lstm_act(aY, cB);
            const float h4 = lstm_act(aZ, cC);
            unsigned w0, w1;
            asm("v_cvt_pk_bf16_f32 %0, %1, %2" : "=v"(w0) : "v"(h2), "v"(h3));
            asm("v_cvt_pk_bf16_f32 %0, %1, %2" : "=v"(w1) : "v"(h4), "v"(fzero));
            *(unsigned*)(lb + (p ^ 1) * BUF + wo23) = w0;
            *(short*)(lb + (p ^ 1) * BUF + wo4) = (short)w1;
        }
        block_sync_lds();                          // h(t) visible for step t+1
    };

    for (int t = 0; t < T; t += 2) {
        body(xfA, t, 0);
        body(xfB, t + 1, 1);
    }

    // final dense for h(T-1): sits in buffer 0 (T even); x rows of afd are zero
    if (wid == 0) {
        union { int4 i; bf16x8 v; } ub;
        ub.i = *(const int4*)(lb + rdo);
        const f32x4 aZ = __builtin_amdgcn_mfma_f32_16x16x32_bf16(afZ, ub.v, z4, 0, 0, 0);
        if (USE_WS) {
            float* pt = pbase + (size_t)(T - 1) * (D * B);
            if (bvalid && g4 == 0) {
                pt[0 * B] = aZ[0]; pt[1 * B] = aZ[1];
                pt[2 * B] = aZ[2]; pt[3 * B] = aZ[3];
            } else if (bvalid && g4 == 1) {
                pt[4 * B] = aZ[0];
            }
        } else {
            float* pt = pbase + (size_t)(T - 1) * D;
            if (bvalid && g4 == 0) {
                atomicAdd(&pt[0], aZ[0]); atomicAdd(&pt[1], aZ[1]);
                atomicAdd(&pt[2], aZ[2]); atomicAdd(&pt[3], aZ[3]);
            } else if (bvalid && g4 == 1) {
                atomicAdd(&pt[4], aZ[0]);
            }
        }
    }
}

// out[b][t][d] = dense_b[d] + sum_n pw[n][t][d][b]  (coalesced reads)
__global__ __launch_bounds__(512) void reduce_kernel(
    const float* __restrict__ pw, const float* __restrict__ dense_b,
    float* __restrict__ out)
{
    const int t    = blockIdx.x;
    const int flat = threadIdx.x;              // d*B + b, 0..499
    if (flat >= B * D) return;
    const int d = flat / B;
    const int b = flat % B;
    const float* p = pw + (size_t)t * (D * B) + flat;
    constexpr size_t stride = (size_t)T * D * B;
    float a0 = 0.0f, a1 = 0.0f;
    #pragma unroll 10
    for (int n = 0; n < NL; n += 2) {
        a0 += p[(size_t)n * stride];
        a1 += p[(size_t)(n + 1) * stride];
    }
    out[((size_t)b * T + t) * D + d] = a0 + a1 + dense_b[d];
}

extern "C" void kernel_launch(void* const* d_in, const int* in_sizes, int n_in,
                              void* d_out, int out_size, void* d_ws, size_t ws_size,
                              hipStream_t stream) {
    const float* x   = (const float*)d_in[0];
    const float* Wg  = (const float*)d_in[1];
    const float* Ug  = (const float*)d_in[2];
    const float* bg  = (const float*)d_in[3];
    const float* dWg = (const float*)d_in[4];
    const float* dbv = (const float*)d_in[5];
    float* out = (float*)d_out;

    const size_t xe_bytes = (size_t)2 * T * BPAD * sizeof(int2);      // 458,752
    const size_t pw_bytes = (size_t)NL * T * D * B * sizeof(float);   // 102.4 MB

    int2* xe = (int2*)d_ws;
    xpack_kernel<<<(2 * T * BPAD + 255) / 256, 256, 0, stream>>>(x, xe);

    if (ws_size >= xe_bytes + pw_bytes) {
        float* pw = (float*)((char*)d_ws + xe_bytes);
        lstm2w_kernel<true><<<NL * NW, 128, 0, stream>>>(xe, Wg, Ug, bg, dWg, pw, out);
        reduce_kernel<<<T, 512, 0, stream>>>(pw, dbv, out);
    } else {
        init_out_kernel<<<(out_size + 255) / 256, 256, 0, stream>>>(dbv, out, out_size);
        lstm2w_kernel<false><<<NL * NW, 128, 0, stream>>>(xe, Wg, Ug, bg, dWg, nullptr, out);
    }
}